// Round 16
// baseline (2297.345 us; speedup 1.0000x reference)
//
#include <hip/hip_runtime.h>

// LSTMCharacterPredictor — round 16 (final): R10 + gatesm double-buffer only.
// T=512 B=64 E=512 H=1024 V=256.
// R15 post-mortem: AGPR pin regressed on 8-wave base (1766 vs 1663) -> R10's
// "+v" config is best. 15-round search bounded the space: detection (flag/
// tag/sentinel/counter), publish (store/atomic), cadence (sleep), topology
// (fan-in 64->32, XCD-local x2 = uncontrollable), W placement, poll
// granularity — the period is the serial all-gather through MALL (~3.2us/
// step latency floor, not a BW/compute roofline). This round: the one clean
// leftover from R14's bundle — double-buffered gatesm drops the trailing WAR
// barrier (correctness via barrier transitivity: step t+2's write of
// buffer[t&1] follows barrier(t+1) which follows all step-t reads).

#define TT 512
#define BB 64
#define HH 1024
#define VV 256
#define EE 512
#define SPIN_CAP 16384

typedef __attribute__((ext_vector_type(8))) short bf16x8;
typedef __attribute__((ext_vector_type(4))) float f32x4;
typedef __attribute__((ext_vector_type(4))) int i32x4;
typedef __attribute__((ext_vector_type(4))) unsigned short u16x4;

static __device__ __forceinline__ unsigned short f2bf(float f) {
  union { float f; unsigned u; } x; x.f = f;
  unsigned r = x.u + 0x7fffu + ((x.u >> 16) & 1u);   // RNE
  return (unsigned short)(r >> 16);
}

// ---------------- f32 -> bf16 convert (vectorized) ----------------
__global__ void cvt_bf16(const float* __restrict__ s, unsigned short* __restrict__ d, int n4) {
  int i = blockIdx.x * blockDim.x + threadIdx.x;
  int st = gridDim.x * blockDim.x;
  for (; i < n4; i += st) {
    f32x4 v = *(const f32x4*)(s + 4l * i);
    u16x4 o;
    o.x = f2bf(v.x); o.y = f2bf(v.y); o.z = f2bf(v.z); o.w = f2bf(v.w);
    *(u16x4*)(d + 4l * i) = o;
  }
}

// ------- proj packed: proj[v][unit][gate] = enc@W_ih^T + b_ih + b_hh -------
__global__ __launch_bounds__(256) void proj_kernel(
    const unsigned short* __restrict__ A,    // enc bf16 [256][512]
    const unsigned short* __restrict__ Wi,   // W_ih bf16 [4096][512]
    const float* __restrict__ bih, const float* __restrict__ bhh,
    float* __restrict__ proj)                // [256][1024][4] f32
{
  __shared__ __align__(16) unsigned char Asm[64 * 128];   // [64 m][64 k] bf16, swizzled
  const int tid = threadIdx.x;
  const int w = tid >> 6;
  const int lane = tid & 63;
  const int ln = lane & 15, kg = lane >> 4;
  const int m0 = blockIdx.x * 64;            // 4 blocks
  const int nb = blockIdx.y * 256 + w * 64;  // 16 blocks.y, wave owns 64 n
  const int srow = tid >> 2, skq = tid & 3;

  f32x4 acc[4][4];
  for (int a = 0; a < 4; ++a) for (int b = 0; b < 4; ++b) acc[a][b] = (f32x4){0.f,0.f,0.f,0.f};

  for (int kc = 0; kc < 8; ++kc) {           // K=512 in chunks of 64
    {
      const unsigned short* src = A + (m0 + srow) * 512 + kc * 64 + skq * 16;
      unsigned base = (unsigned)(srow * 128 + skq * 32);
      unsigned sw = (unsigned)((srow & 7) << 4);
      *(i32x4*)(Asm + ((base) ^ sw))      = *(const i32x4*)(src);
      *(i32x4*)(Asm + ((base + 16) ^ sw)) = *(const i32x4*)(src + 8);
    }
    __syncthreads();
    for (int kk = 0; kk < 2; ++kk) {
      bf16x8 afr[4];
      for (int mi = 0; mi < 4; ++mi) {
        int row = mi * 16 + ln;
        unsigned off = (unsigned)(row * 128 + (kk * 32 + kg * 8) * 2);
        afr[mi] = *(const bf16x8*)(Asm + (off ^ ((unsigned)(row & 7) << 4)));
      }
      for (int ni = 0; ni < 4; ++ni) {
        const unsigned short* bp = Wi + (nb + ni * 16 + ln) * 512 + kc * 64 + kk * 32 + kg * 8;
        bf16x8 bfr = *(const bf16x8*)bp;
        for (int mi = 0; mi < 4; ++mi)
          acc[mi][ni] = __builtin_amdgcn_mfma_f32_16x16x32_bf16(afr[mi], bfr, acc[mi][ni], 0, 0, 0);
      }
    }
    __syncthreads();
  }
  for (int ni = 0; ni < 4; ++ni) {
    int nn = nb + ni * 16 + ln;             // global gate-row = gi*1024 + unit
    int gi = nn >> 10, uu = nn & 1023;
    float bias = bih[nn] + bhh[nn];
    for (int mi = 0; mi < 4; ++mi) {
      int mr = m0 + mi * 16 + kg * 4;
      for (int r = 0; r < 4; ++r)
        proj[(size_t)(mr + r) * 4096 + uu * 4 + gi] = acc[mi][ni][r] + bias;
    }
  }
}

// ---------------- persistent LSTM scan (R10 + dbuf gatesm) ----------------
// group g=blk&7 owns samples [g*8,+8); slice r=blk>>3 owns units [r*32,+32).
// 512 thr / 8 waves; wave w: K-slice [w*128,+128), bw[8][4] (VGPR, "+v" pin).
// hcomm[slot][sample][unit] = (bf16 h)<<16 | version, slot=version&1.
// One barrier per step: gatesm double-buffered on t&1.
__global__ __launch_bounds__(512, 2) void scan_kernel(
    const unsigned short* __restrict__ Whh,   // bf16 [4096][1024]
    const float* __restrict__ proj,           // [256][1024][4] f32 packed
    const int* __restrict__ ints,             // [512][64]
    const float* __restrict__ h0v,            // output0 [1024]
    const float* __restrict__ c0v,            // memory0 [1024]
    unsigned int* __restrict__ hcomm,         // [2][64][1024] tagged u32
    unsigned short* __restrict__ outs)        // bf16 [512][64][1024] h history
{
  __shared__ float gatesm[2 * 8 * 8 * 128];   // dbuf x [wave][sample][localrow] 64 KB

  const int tid = threadIdx.x;
  const int blk = blockIdx.x;
  const int g = blk & 7, r = blk >> 3;        // XCD-affine heuristic mapping
  const int w = tid >> 6, lane = tid & 63;
  const int ln = lane & 15, kg = lane >> 4;
  const int s = (tid & 255) >> 5, u = tid & 31;  // elementwise cell (tid<256)
  const int sg = g * 8 + s;
  const int ug = r * 32 + u;

  // W_hh B-frags: local gate-row lrow=nt*16+ln -> global row
  // (lrow>>5)*1024 + r*32 + (lrow&31); k = w*128 + kt*32 + kg*8 + [0,8).
  bf16x8 bw[8][4];
#pragma unroll
  for (int nt = 0; nt < 8; ++nt) {
    int lrow = nt * 16 + ln;
    int grow = (lrow >> 5) * 1024 + r * 32 + (lrow & 31);
    const unsigned short* wp = Whh + (size_t)grow * 1024 + w * 128 + kg * 8;
#pragma unroll
    for (int kt = 0; kt < 4; ++kt)
      bw[nt][kt] = *(const bf16x8*)(wp + kt * 32);
  }
  // pin against rematerialization (R10 config: "+v")
#pragma unroll
  for (int nt = 0; nt < 8; ++nt)
#pragma unroll
    for (int kt = 0; kt < 4; ++kt)
      asm volatile("" : "+v"(bw[nt][kt]));

  float c = (tid < 256) ? c0v[ug] : 0.f;

  // publish version 1 (= h0) into slot 1; outs[0]  (tid<256: one per (s,u))
  if (tid < 256) {
    unsigned short hb = f2bf(h0v[ug]);
    unsigned word = ((unsigned)hb << 16) | 1u;
    unsigned* hp = hcomm + 65536 + (size_t)sg * 1024 + ug;
    asm volatile("global_store_dword %0, %1, off sc0 sc1" :: "v"(hp), "v"(word) : "memory");
    outs[(size_t)sg * 1024 + ug] = hb;
  }

  i32x4 q[8];
#pragma unroll
  for (int i = 0; i < 8; ++i) q[i] = (i32x4){0, 0, 0, 0};

  for (int t = 0; t < TT - 1; ++t) {
    // ---- prefetch packed proj (tid<256; poll's vmcnt drains it) ----
    f32x4 prv = (f32x4){0.f,0.f,0.f,0.f};
    if (tid < 256) {
      int vocab = ints[t * 64 + sg];
      const float* pp = proj + (size_t)vocab * 4096 + ug * 4;
      asm volatile("global_load_dwordx4 %0, %1, off" : "=v"(prv) : "v"(pp) : "memory");
    }

    // ---- poll A-rows (lanes ln<8 = real samples; ln>=8 pads keep q=0) ----
    const unsigned* ab = hcomm + ((size_t)((t + 1) & 1)) * 65536
                       + (size_t)(g * 8 + (ln & 7)) * 1024 + w * 128 + kg * 8;
    unsigned tgt = (unsigned)(t + 1);
    {
      int guard = 0;
      while (true) {
        if (ln < 8) {
#define LQ(i, off_lit) \
          asm volatile("global_load_dwordx4 %0, %1, off offset:" off_lit " sc0 sc1" \
                       : "=v"(q[i]) : "v"(ab) : "memory")
          LQ(0, "0");   LQ(1, "16");  LQ(2, "128"); LQ(3, "144");
          LQ(4, "256"); LQ(5, "272"); LQ(6, "384"); LQ(7, "400");
#undef LQ
        }
        asm volatile("s_waitcnt vmcnt(0)" ::: "memory");
        __builtin_amdgcn_sched_barrier(0);    // rule 18: keep checks after wait
        unsigned bad = 0;
        if (ln < 8) {
#pragma unroll
          for (int i = 0; i < 8; ++i) {
            bad |= ((unsigned)q[i].x ^ tgt);
            bad |= ((unsigned)q[i].y ^ tgt);
            bad |= ((unsigned)q[i].z ^ tgt);
            bad |= ((unsigned)q[i].w ^ tgt);
          }
        }
        if (__all(ln >= 8 || (bad & 0xffffu) == 0u)) break;
        if (++guard > SPIN_CAP) break;        // deadlock escape (never legit)
      }
    }
    __builtin_amdgcn_sched_barrier(0);

    // ---- unpack + 32 MFMAs/wave (8 independent n-tile chains) ----
    f32x4 acc[8];
#pragma unroll
    for (int i = 0; i < 8; ++i) acc[i] = (f32x4){0.f,0.f,0.f,0.f};
#pragma unroll
    for (int kt = 0; kt < 4; ++kt) {
      i32x4 lo = q[2 * kt], hi = q[2 * kt + 1];
      unsigned d0 = ((unsigned)lo.x >> 16) | ((unsigned)lo.y & 0xffff0000u);
      unsigned d1 = ((unsigned)lo.z >> 16) | ((unsigned)lo.w & 0xffff0000u);
      unsigned d2 = ((unsigned)hi.x >> 16) | ((unsigned)hi.y & 0xffff0000u);
      unsigned d3 = ((unsigned)hi.z >> 16) | ((unsigned)hi.w & 0xffff0000u);
      union { i32x4 i; bf16x8 h; } u2;
      u2.i = (i32x4){ (int)d0, (int)d1, (int)d2, (int)d3 };
#pragma unroll
      for (int nt = 0; nt < 8; ++nt)
        acc[nt] = __builtin_amdgcn_mfma_f32_16x16x32_bf16(u2.h, bw[nt][kt], acc[nt], 0, 0, 0);
    }

    // ---- partials to LDS (dbuf t&1): m=kg*4+rr (sample<8), n=nt*16+ln ----
    float* gm0 = gatesm + (t & 1) * 8192;
#pragma unroll
    for (int nt = 0; nt < 8; ++nt) {
      if (kg < 2) {
#pragma unroll
        for (int rr = 0; rr < 4; ++rr)
          gm0[(w * 8 + kg * 4 + rr) * 128 + nt * 16 + ln] = acc[nt][rr];
      }
    }
    __syncthreads();   // the ONE barrier per step

    // ---- elementwise cell update + publish (tid<256, thread (s,u)) ----
    if (tid < 256) {
      float g0 = prv.x, g1 = prv.y, g2 = prv.z, g3 = prv.w;
#pragma unroll
      for (int ww = 0; ww < 8; ++ww) {
        const float* gp = gm0 + (ww * 8 + s) * 128 + u;
        g0 += gp[0];     // gate i: localrow u
        g1 += gp[32];    // gate f
        g2 += gp[64];    // gate g
        g3 += gp[96];    // gate o
      }
      float ii = __builtin_amdgcn_rcpf(1.f + __expf(-g0));
      float ff = __builtin_amdgcn_rcpf(1.f + __expf(-g1));
      float gt = 1.f - 2.f * __builtin_amdgcn_rcpf(1.f + __expf(2.f * g2));
      float oo = __builtin_amdgcn_rcpf(1.f + __expf(-g3));
      c = ff * c + ii * gt;
      float hv = oo * (1.f - 2.f * __builtin_amdgcn_rcpf(1.f + __expf(2.f * c)));

      unsigned short hb = f2bf(hv);
      unsigned word = ((unsigned)hb << 16) | ((unsigned)(t + 2) & 0xffffu);
      unsigned* hp = hcomm + ((size_t)((t + 2) & 1)) * 65536 + (size_t)sg * 1024 + ug;
      asm volatile("global_store_dword %0, %1, off sc0 sc1" :: "v"(hp), "v"(word) : "memory");
      outs[(size_t)(t + 1) * 65536 + (size_t)sg * 1024 + ug] = hb;
    }
    // no trailing barrier: buffer[t&1] is next written in step t+2, which is
    // after barrier(t+1), which is after every wave's step-t read. (R14-proven)
  }
}

// ---------------- decode: out[32768,256] = outs_bf @ W_dec^T + b_dec ----------------
__global__ __launch_bounds__(256) void decode_kernel(
    const unsigned short* __restrict__ A,    // outs bf16 [32768][1024]
    const unsigned short* __restrict__ Wd,   // W_dec bf16 [256][1024]
    const float* __restrict__ bdec,
    float* __restrict__ out)                 // [32768][256]
{
  __shared__ __align__(16) unsigned char Asm[64 * 128];
  const int tid = threadIdx.x;
  const int w = tid >> 6;
  const int lane = tid & 63;
  const int ln = lane & 15, kg = lane >> 4;
  const int m0 = blockIdx.x * 64;
  const int nb = w * 64;                     // 4 waves cover N=256
  const int srow = tid >> 2, skq = tid & 3;

  f32x4 acc[4][4];
  for (int a = 0; a < 4; ++a) for (int b = 0; b < 4; ++b) acc[a][b] = (f32x4){0.f,0.f,0.f,0.f};

  for (int kc = 0; kc < 16; ++kc) {          // K=1024 in chunks of 64
    {
      const unsigned short* src = A + (m0 + srow) * 1024 + kc * 64 + skq * 16;
      unsigned base = (unsigned)(srow * 128 + skq * 32);
      unsigned sw = (unsigned)((srow & 7) << 4);
      *(i32x4*)(Asm + ((base) ^ sw))      = *(const i32x4*)(src);
      *(i32x4*)(Asm + ((base + 16) ^ sw)) = *(const i32x4*)(src + 8);
    }
    __syncthreads();
    for (int kk = 0; kk < 2; ++kk) {
      bf16x8 afr[4];
      for (int mi = 0; mi < 4; ++mi) {
        int row = mi * 16 + ln;
        unsigned off = (unsigned)(row * 128 + (kk * 32 + kg * 8) * 2);
        afr[mi] = *(const bf16x8*)(Asm + (off ^ ((unsigned)(row & 7) << 4)));
      }
      for (int ni = 0; ni < 4; ++ni) {
        const unsigned short* bp = Wd + (nb + ni * 16 + ln) * 1024 + kc * 64 + kk * 32 + kg * 8;
        bf16x8 bfr = *(const bf16x8*)bp;
        for (int mi = 0; mi < 4; ++mi)
          acc[mi][ni] = __builtin_amdgcn_mfma_f32_16x16x32_bf16(afr[mi], bfr, acc[mi][ni], 0, 0, 0);
      }
    }
    __syncthreads();
  }
  for (int ni = 0; ni < 4; ++ni) {
    int nn = nb + ni * 16 + ln;
    float bd = bdec[nn];
    for (int mi = 0; mi < 4; ++mi) {
      int mr = m0 + mi * 16 + kg * 4;
      for (int r = 0; r < 4; ++r)
        out[(mr + r) * 256 + nn] = acc[mi][ni][r] + bd;
    }
  }
}

// ---------------- host ----------------
extern "C" void kernel_launch(void* const* d_in, const int* in_sizes, int n_in,
                              void* d_out, int out_size, void* d_ws, size_t ws_size,
                              hipStream_t stream) {
  const int*   ints = (const int*)  d_in[0];
  const float* enc  = (const float*)d_in[1];
  const float* out0 = (const float*)d_in[2];
  const float* mem0 = (const float*)d_in[3];
  const float* Wih  = (const float*)d_in[4];
  const float* Whh  = (const float*)d_in[5];
  const float* bih  = (const float*)d_in[6];
  const float* bhh  = (const float*)d_in[7];
  const float* Wdec = (const float*)d_in[8];
  const float* bdec = (const float*)d_in[9];
  float* out = (float*)d_out;

  char* ws = (char*)d_ws;
  size_t off = 0;
  auto alloc = [&](size_t bytes) { char* p = ws + off; off += (bytes + 255) & ~(size_t)255; return p; };
  unsigned short* Whh_bf  = (unsigned short*)alloc(4096ull * 1024 * 2);     // 8 MB
  unsigned short* enc_bf  = (unsigned short*)alloc(256ull * 512 * 2);
  unsigned short* Wih_bf  = (unsigned short*)alloc(4096ull * 512 * 2);      // 4 MB
  unsigned short* Wdec_bf = (unsigned short*)alloc(256ull * 1024 * 2);
  float*          proj    = (float*)alloc(256ull * 4096 * 4);               // 4 MB packed
  unsigned short* outs_bf = (unsigned short*)alloc(512ull * 64 * 1024 * 2); // 64 MB
  unsigned int*   hcomm   = (unsigned int*)alloc(2ull * 64 * 1024 * 4);     // 512 KB
  // total ~81 MB of ws

  // Zero the tag ring every launch (first call sees recycled ws garbage;
  // tag 0 never matches any target).
  hipMemsetAsync(hcomm, 0, 2ull * 64 * 1024 * 4, stream);

  cvt_bf16<<<512, 256, 0, stream>>>(Whh,  Whh_bf,  4096 * 1024 / 4);
  cvt_bf16<<<64,  256, 0, stream>>>(enc,  enc_bf,  256 * 512 / 4);
  cvt_bf16<<<256, 256, 0, stream>>>(Wih,  Wih_bf,  4096 * 512 / 4);
  cvt_bf16<<<64,  256, 0, stream>>>(Wdec, Wdec_bf, 256 * 1024 / 4);

  proj_kernel<<<dim3(4, 16), 256, 0, stream>>>(enc_bf, Wih_bf, bih, bhh, proj);

  {
    const unsigned short* a0 = Whh_bf;
    const float* a1 = proj;
    const int* a2 = ints;
    const float* a3 = out0;
    const float* a4 = mem0;
    unsigned int* a5 = hcomm;
    unsigned short* a6 = outs_bf;
    void* args[] = { &a0, &a1, &a2, &a3, &a4, &a5, &a6 };
    hipError_t e = hipLaunchCooperativeKernel((const void*)scan_kernel,
                                              dim3(256), dim3(512), args, 0, stream);
    if (e != hipSuccess) {
      // fallback: plain launch; ~124 VGPR, 64KB LDS -> 1 blk/CU, 256 co-resident
      scan_kernel<<<256, 512, 0, stream>>>(Whh_bf, proj, ints, out0, mem0,
                                           hcomm, outs_bf);
    }
  }

  decode_kernel<<<512, 256, 0, stream>>>(outs_bf, Wdec_bf, bdec, out);
}

// Round 17
// 1711.260 us; speedup vs baseline: 1.3425x; 1.3425x over previous
//
#include <hip/hip_runtime.h>

// LSTMCharacterPredictor — round 17 (FINAL): exact restore of R10, the
// verified best (1663us scan / 1709us total, 3.25us/step).
// T=512 B=64 E=512 H=1024 V=256.
// Search summary (16 rounds): persistent-scan, 8 groups x 32 blocks x 8
// waves; tagged sc1 data-poll depth-2 ring (fused detect+load) is the
// minimal global chain. All neighbors regress: AGPR W pin (R15 +6%),
// incremental poll (R14 +13%), barrier removal (R16 +35%), counter detect
// (R12 +47%), sentinel/atomic (R5), sleep (R6), XCD-local sc0 (R7/R13:
// uncontrollable from HIP). Period = MALL-crossing latency floor for a
// 511-step serial recurrence; HBM 2.8% / MfmaUtil 13.6% => not a roofline.

#define TT 512
#define BB 64
#define HH 1024
#define VV 256
#define EE 512
#define SPIN_CAP 16384

typedef __attribute__((ext_vector_type(8))) short bf16x8;
typedef __attribute__((ext_vector_type(4))) float f32x4;
typedef __attribute__((ext_vector_type(4))) int i32x4;
typedef __attribute__((ext_vector_type(4))) unsigned short u16x4;

static __device__ __forceinline__ unsigned short f2bf(float f) {
  union { float f; unsigned u; } x; x.f = f;
  unsigned r = x.u + 0x7fffu + ((x.u >> 16) & 1u);   // RNE
  return (unsigned short)(r >> 16);
}

// ---------------- f32 -> bf16 convert (vectorized) ----------------
__global__ void cvt_bf16(const float* __restrict__ s, unsigned short* __restrict__ d, int n4) {
  int i = blockIdx.x * blockDim.x + threadIdx.x;
  int st = gridDim.x * blockDim.x;
  for (; i < n4; i += st) {
    f32x4 v = *(const f32x4*)(s + 4l * i);
    u16x4 o;
    o.x = f2bf(v.x); o.y = f2bf(v.y); o.z = f2bf(v.z); o.w = f2bf(v.w);
    *(u16x4*)(d + 4l * i) = o;
  }
}

// ------- proj packed: proj[v][unit][gate] = enc@W_ih^T + b_ih + b_hh -------
__global__ __launch_bounds__(256) void proj_kernel(
    const unsigned short* __restrict__ A,    // enc bf16 [256][512]
    const unsigned short* __restrict__ Wi,   // W_ih bf16 [4096][512]
    const float* __restrict__ bih, const float* __restrict__ bhh,
    float* __restrict__ proj)                // [256][1024][4] f32
{
  __shared__ __align__(16) unsigned char Asm[64 * 128];   // [64 m][64 k] bf16, swizzled
  const int tid = threadIdx.x;
  const int w = tid >> 6;
  const int lane = tid & 63;
  const int ln = lane & 15, kg = lane >> 4;
  const int m0 = blockIdx.x * 64;            // 4 blocks
  const int nb = blockIdx.y * 256 + w * 64;  // 16 blocks.y, wave owns 64 n
  const int srow = tid >> 2, skq = tid & 3;

  f32x4 acc[4][4];
  for (int a = 0; a < 4; ++a) for (int b = 0; b < 4; ++b) acc[a][b] = (f32x4){0.f,0.f,0.f,0.f};

  for (int kc = 0; kc < 8; ++kc) {           // K=512 in chunks of 64
    {
      const unsigned short* src = A + (m0 + srow) * 512 + kc * 64 + skq * 16;
      unsigned base = (unsigned)(srow * 128 + skq * 32);
      unsigned sw = (unsigned)((srow & 7) << 4);
      *(i32x4*)(Asm + ((base) ^ sw))      = *(const i32x4*)(src);
      *(i32x4*)(Asm + ((base + 16) ^ sw)) = *(const i32x4*)(src + 8);
    }
    __syncthreads();
    for (int kk = 0; kk < 2; ++kk) {
      bf16x8 afr[4];
      for (int mi = 0; mi < 4; ++mi) {
        int row = mi * 16 + ln;
        unsigned off = (unsigned)(row * 128 + (kk * 32 + kg * 8) * 2);
        afr[mi] = *(const bf16x8*)(Asm + (off ^ ((unsigned)(row & 7) << 4)));
      }
      for (int ni = 0; ni < 4; ++ni) {
        const unsigned short* bp = Wi + (nb + ni * 16 + ln) * 512 + kc * 64 + kk * 32 + kg * 8;
        bf16x8 bfr = *(const bf16x8*)bp;
        for (int mi = 0; mi < 4; ++mi)
          acc[mi][ni] = __builtin_amdgcn_mfma_f32_16x16x32_bf16(afr[mi], bfr, acc[mi][ni], 0, 0, 0);
      }
    }
    __syncthreads();
  }
  for (int ni = 0; ni < 4; ++ni) {
    int nn = nb + ni * 16 + ln;             // global gate-row = gi*1024 + unit
    int gi = nn >> 10, uu = nn & 1023;
    float bias = bih[nn] + bhh[nn];
    for (int mi = 0; mi < 4; ++mi) {
      int mr = m0 + mi * 16 + kg * 4;
      for (int r = 0; r < 4; ++r)
        proj[(size_t)(mr + r) * 4096 + uu * 4 + gi] = acc[mi][ni][r] + bias;
    }
  }
}

// ---------------- persistent LSTM scan (8 waves) ----------------
// group g=blk&7 owns samples [g*8,+8); slice r=blk>>3 owns units [r*32,+32).
// Wave w in [0,8): K-slice [w*128,+128) of the 128 local gate rows.
// bw[8 n-tiles][4 k-tiles] = 128 VGPRs. MFMA M=16: rows 0..7 real samples.
// hcomm[slot][sample][unit] = (bf16 h)<<16 | version, slot=version&1.
__global__ __launch_bounds__(512, 2) void scan_kernel(
    const unsigned short* __restrict__ Whh,   // bf16 [4096][1024]
    const float* __restrict__ proj,           // [256][1024][4] f32 packed
    const int* __restrict__ ints,             // [512][64]
    const float* __restrict__ h0v,            // output0 [1024]
    const float* __restrict__ c0v,            // memory0 [1024]
    unsigned int* __restrict__ hcomm,         // [2][64][1024] tagged u32
    unsigned short* __restrict__ outs)        // bf16 [512][64][1024] h history
{
  __shared__ float gatesm[8 * 8 * 128];       // [wave][sample(8)][localrow(128)] 32 KB

  const int tid = threadIdx.x;
  const int blk = blockIdx.x;
  const int g = blk & 7, r = blk >> 3;        // XCD-affine heuristic mapping
  const int w = tid >> 6, lane = tid & 63;
  const int ln = lane & 15, kg = lane >> 4;
  const int s = (tid & 255) >> 5, u = tid & 31;  // elementwise cell (tid<256)
  const int sg = g * 8 + s;
  const int ug = r * 32 + u;

  // W_hh B-frags: local gate-row lrow=nt*16+ln -> global row
  // (lrow>>5)*1024 + r*32 + (lrow&31); k = w*128 + kt*32 + kg*8 + [0,8).
  bf16x8 bw[8][4];
#pragma unroll
  for (int nt = 0; nt < 8; ++nt) {
    int lrow = nt * 16 + ln;
    int grow = (lrow >> 5) * 1024 + r * 32 + (lrow & 31);
    const unsigned short* wp = Whh + (size_t)grow * 1024 + w * 128 + kg * 8;
#pragma unroll
    for (int kt = 0; kt < 4; ++kt)
      bw[nt][kt] = *(const bf16x8*)(wp + kt * 32);
  }
  // pin against rematerialization
#pragma unroll
  for (int nt = 0; nt < 8; ++nt)
#pragma unroll
    for (int kt = 0; kt < 4; ++kt)
      asm volatile("" : "+v"(bw[nt][kt]));

  float c = (tid < 256) ? c0v[ug] : 0.f;

  // publish version 1 (= h0) into slot 1; outs[0]  (tid<256: one per (s,u))
  if (tid < 256) {
    unsigned short hb = f2bf(h0v[ug]);
    unsigned word = ((unsigned)hb << 16) | 1u;
    unsigned* hp = hcomm + 65536 + (size_t)sg * 1024 + ug;
    asm volatile("global_store_dword %0, %1, off sc0 sc1" :: "v"(hp), "v"(word) : "memory");
    outs[(size_t)sg * 1024 + ug] = hb;
  }

  i32x4 q[8];
#pragma unroll
  for (int i = 0; i < 8; ++i) q[i] = (i32x4){0, 0, 0, 0};

  for (int t = 0; t < TT - 1; ++t) {
    // ---- prefetch packed proj (tid<256; poll's vmcnt drains it) ----
    f32x4 prv = (f32x4){0.f,0.f,0.f,0.f};
    if (tid < 256) {
      int vocab = ints[t * 64 + sg];
      const float* pp = proj + (size_t)vocab * 4096 + ug * 4;
      asm volatile("global_load_dwordx4 %0, %1, off" : "=v"(prv) : "v"(pp) : "memory");
    }

    // ---- poll A-rows (lanes ln<8 = real samples; ln>=8 pads keep q=0) ----
    const unsigned* ab = hcomm + ((size_t)((t + 1) & 1)) * 65536
                       + (size_t)(g * 8 + (ln & 7)) * 1024 + w * 128 + kg * 8;
    unsigned tgt = (unsigned)(t + 1);
    {
      int guard = 0;
      while (true) {
        if (ln < 8) {
#define LQ(i, off_lit) \
          asm volatile("global_load_dwordx4 %0, %1, off offset:" off_lit " sc0 sc1" \
                       : "=v"(q[i]) : "v"(ab) : "memory")
          LQ(0, "0");   LQ(1, "16");  LQ(2, "128"); LQ(3, "144");
          LQ(4, "256"); LQ(5, "272"); LQ(6, "384"); LQ(7, "400");
#undef LQ
        }
        asm volatile("s_waitcnt vmcnt(0)" ::: "memory");
        __builtin_amdgcn_sched_barrier(0);    // rule 18: keep checks after wait
        unsigned bad = 0;
        if (ln < 8) {
#pragma unroll
          for (int i = 0; i < 8; ++i) {
            bad |= ((unsigned)q[i].x ^ tgt);
            bad |= ((unsigned)q[i].y ^ tgt);
            bad |= ((unsigned)q[i].z ^ tgt);
            bad |= ((unsigned)q[i].w ^ tgt);
          }
        }
        if (__all(ln >= 8 || (bad & 0xffffu) == 0u)) break;
        if (++guard > SPIN_CAP) break;        // deadlock escape (never legit)
      }
    }
    __builtin_amdgcn_sched_barrier(0);

    // ---- unpack + 32 MFMAs/wave (8 independent n-tile chains) ----
    f32x4 acc[8];
#pragma unroll
    for (int i = 0; i < 8; ++i) acc[i] = (f32x4){0.f,0.f,0.f,0.f};
#pragma unroll
    for (int kt = 0; kt < 4; ++kt) {
      i32x4 lo = q[2 * kt], hi = q[2 * kt + 1];
      unsigned d0 = ((unsigned)lo.x >> 16) | ((unsigned)lo.y & 0xffff0000u);
      unsigned d1 = ((unsigned)lo.z >> 16) | ((unsigned)lo.w & 0xffff0000u);
      unsigned d2 = ((unsigned)hi.x >> 16) | ((unsigned)hi.y & 0xffff0000u);
      unsigned d3 = ((unsigned)hi.z >> 16) | ((unsigned)hi.w & 0xffff0000u);
      union { i32x4 i; bf16x8 h; } u2;
      u2.i = (i32x4){ (int)d0, (int)d1, (int)d2, (int)d3 };
#pragma unroll
      for (int nt = 0; nt < 8; ++nt)
        acc[nt] = __builtin_amdgcn_mfma_f32_16x16x32_bf16(u2.h, bw[nt][kt], acc[nt], 0, 0, 0);
    }

    // ---- partials to LDS: m=kg*4+rr (sample, keep m<8), n=nt*16+ln ----
#pragma unroll
    for (int nt = 0; nt < 8; ++nt) {
      if (kg < 2) {
#pragma unroll
        for (int rr = 0; rr < 4; ++rr)
          gatesm[(w * 8 + kg * 4 + rr) * 128 + nt * 16 + ln] = acc[nt][rr];
      }
    }
    __syncthreads();

    // ---- elementwise cell update: tid<256, thread (s,u) ----
    if (tid < 256) {
      float g0 = prv.x, g1 = prv.y, g2 = prv.z, g3 = prv.w;
#pragma unroll
      for (int ww = 0; ww < 8; ++ww) {
        const float* gm = gatesm + (ww * 8 + s) * 128 + u;
        g0 += gm[0];     // gate i: localrow u
        g1 += gm[32];    // gate f
        g2 += gm[64];    // gate g
        g3 += gm[96];    // gate o
      }
      float ii = __builtin_amdgcn_rcpf(1.f + __expf(-g0));
      float ff = __builtin_amdgcn_rcpf(1.f + __expf(-g1));
      float gt = 1.f - 2.f * __builtin_amdgcn_rcpf(1.f + __expf(2.f * g2));
      float oo = __builtin_amdgcn_rcpf(1.f + __expf(-g3));
      c = ff * c + ii * gt;
      float hv = oo * (1.f - 2.f * __builtin_amdgcn_rcpf(1.f + __expf(2.f * c)));

      // ---- publish version t+2 + outs[t+1] ----
      unsigned short hb = f2bf(hv);
      unsigned word = ((unsigned)hb << 16) | ((unsigned)(t + 2) & 0xffffu);
      unsigned* hp = hcomm + ((size_t)((t + 2) & 1)) * 65536 + (size_t)sg * 1024 + ug;
      asm volatile("global_store_dword %0, %1, off sc0 sc1" :: "v"(hp), "v"(word) : "memory");
      outs[(size_t)(t + 1) * 65536 + (size_t)sg * 1024 + ug] = hb;
    }
    __syncthreads();   // WAR guard for gatesm across steps
  }
}

// ---------------- decode: out[32768,256] = outs_bf @ W_dec^T + b_dec ----------------
__global__ __launch_bounds__(256) void decode_kernel(
    const unsigned short* __restrict__ A,    // outs bf16 [32768][1024]
    const unsigned short* __restrict__ Wd,   // W_dec bf16 [256][1024]
    const float* __restrict__ bdec,
    float* __restrict__ out)                 // [32768][256]
{
  __shared__ __align__(16) unsigned char Asm[64 * 128];
  const int tid = threadIdx.x;
  const int w = tid >> 6;
  const int lane = tid & 63;
  const int ln = lane & 15, kg = lane >> 4;
  const int m0 = blockIdx.x * 64;
  const int nb = w * 64;                     // 4 waves cover N=256
  const int srow = tid >> 2, skq = tid & 3;

  f32x4 acc[4][4];
  for (int a = 0; a < 4; ++a) for (int b = 0; b < 4; ++b) acc[a][b] = (f32x4){0.f,0.f,0.f,0.f};

  for (int kc = 0; kc < 16; ++kc) {          // K=1024 in chunks of 64
    {
      const unsigned short* src = A + (m0 + srow) * 1024 + kc * 64 + skq * 16;
      unsigned base = (unsigned)(srow * 128 + skq * 32);
      unsigned sw = (unsigned)((srow & 7) << 4);
      *(i32x4*)(Asm + ((base) ^ sw))      = *(const i32x4*)(src);
      *(i32x4*)(Asm + ((base + 16) ^ sw)) = *(const i32x4*)(src + 8);
    }
    __syncthreads();
    for (int kk = 0; kk < 2; ++kk) {
      bf16x8 afr[4];
      for (int mi = 0; mi < 4; ++mi) {
        int row = mi * 16 + ln;
        unsigned off = (unsigned)(row * 128 + (kk * 32 + kg * 8) * 2);
        afr[mi] = *(const bf16x8*)(Asm + (off ^ ((unsigned)(row & 7) << 4)));
      }
      for (int ni = 0; ni < 4; ++ni) {
        const unsigned short* bp = Wd + (nb + ni * 16 + ln) * 1024 + kc * 64 + kk * 32 + kg * 8;
        bf16x8 bfr = *(const bf16x8*)bp;
        for (int mi = 0; mi < 4; ++mi)
          acc[mi][ni] = __builtin_amdgcn_mfma_f32_16x16x32_bf16(afr[mi], bfr, acc[mi][ni], 0, 0, 0);
      }
    }
    __syncthreads();
  }
  for (int ni = 0; ni < 4; ++ni) {
    int nn = nb + ni * 16 + ln;
    float bd = bdec[nn];
    for (int mi = 0; mi < 4; ++mi) {
      int mr = m0 + mi * 16 + kg * 4;
      for (int r = 0; r < 4; ++r)
        out[(mr + r) * 256 + nn] = acc[mi][ni][r] + bd;
    }
  }
}

// ---------------- host ----------------
extern "C" void kernel_launch(void* const* d_in, const int* in_sizes, int n_in,
                              void* d_out, int out_size, void* d_ws, size_t ws_size,
                              hipStream_t stream) {
  const int*   ints = (const int*)  d_in[0];
  const float* enc  = (const float*)d_in[1];
  const float* out0 = (const float*)d_in[2];
  const float* mem0 = (const float*)d_in[3];
  const float* Wih  = (const float*)d_in[4];
  const float* Whh  = (const float*)d_in[5];
  const float* bih  = (const float*)d_in[6];
  const float* bhh  = (const float*)d_in[7];
  const float* Wdec = (const float*)d_in[8];
  const float* bdec = (const float*)d_in[9];
  float* out = (float*)d_out;

  char* ws = (char*)d_ws;
  size_t off = 0;
  auto alloc = [&](size_t bytes) { char* p = ws + off; off += (bytes + 255) & ~(size_t)255; return p; };
  unsigned short* Whh_bf  = (unsigned short*)alloc(4096ull * 1024 * 2);     // 8 MB
  unsigned short* enc_bf  = (unsigned short*)alloc(256ull * 512 * 2);
  unsigned short* Wih_bf  = (unsigned short*)alloc(4096ull * 512 * 2);      // 4 MB
  unsigned short* Wdec_bf = (unsigned short*)alloc(256ull * 1024 * 2);
  float*          proj    = (float*)alloc(256ull * 4096 * 4);               // 4 MB packed
  unsigned short* outs_bf = (unsigned short*)alloc(512ull * 64 * 1024 * 2); // 64 MB
  unsigned int*   hcomm   = (unsigned int*)alloc(2ull * 64 * 1024 * 4);     // 512 KB
  // total ~81 MB of ws

  // Zero the tag ring every launch (first call sees recycled ws garbage;
  // tag 0 never matches any target).
  hipMemsetAsync(hcomm, 0, 2ull * 64 * 1024 * 4, stream);

  cvt_bf16<<<512, 256, 0, stream>>>(Whh,  Whh_bf,  4096 * 1024 / 4);
  cvt_bf16<<<64,  256, 0, stream>>>(enc,  enc_bf,  256 * 512 / 4);
  cvt_bf16<<<256, 256, 0, stream>>>(Wih,  Wih_bf,  4096 * 512 / 4);
  cvt_bf16<<<64,  256, 0, stream>>>(Wdec, Wdec_bf, 256 * 1024 / 4);

  proj_kernel<<<dim3(4, 16), 256, 0, stream>>>(enc_bf, Wih_bf, bih, bhh, proj);

  {
    const unsigned short* a0 = Whh_bf;
    const float* a1 = proj;
    const int* a2 = ints;
    const float* a3 = out0;
    const float* a4 = mem0;
    unsigned int* a5 = hcomm;
    unsigned short* a6 = outs_bf;
    void* args[] = { &a0, &a1, &a2, &a3, &a4, &a5, &a6 };
    hipError_t e = hipLaunchCooperativeKernel((const void*)scan_kernel,
                                              dim3(256), dim3(512), args, 0, stream);
    if (e != hipSuccess) {
      // fallback: plain launch; 512 thr x ~124 VGPR -> 1 blk/CU, 256 co-resident
      scan_kernel<<<256, 512, 0, stream>>>(Whh_bf, proj, ints, out0, mem0,
                                           hcomm, outs_bf);
    }
  }

  decode_kernel<<<512, 256, 0, stream>>>(outs_bf, Wdec_bf, bdec, out);
}